// Round 4
// baseline (1737.410 us; speedup 1.0000x reference)
//
#include <hip/hip_runtime.h>
#include <math.h>

#define B_ 64
#define N_ 29
#define E_ 812
#define L_ 9
#define H_ 256
#define FA_ 5
#define BN_ (B_*N_)   // 1856
#define BE_ (B_*E_)   // 51968
#define DEG_ 28
#define SCALE_ 15.0f

typedef __attribute__((ext_vector_type(8))) short bf16x8;
typedef __attribute__((ext_vector_type(4))) float f32x4;

__device__ __forceinline__ float sigmoidf_(float v){ return 1.0f/(1.0f+expf(-v)); }
__device__ __forceinline__ float siluf_(float v){ return v/(1.0f+expf(-v)); }

// bf16 round-to-nearest-even conversion + back
__device__ __forceinline__ ushort f2bf(float f){
    uint u = __float_as_uint(f);
    u += 0x7fffu + ((u>>16)&1u);
    return (ushort)(u>>16);
}
__device__ __forceinline__ float bf2f(ushort h){ return __uint_as_float(((uint)h)<<16); }

// ---------------- init ----------------
__global__ void k_init_h(const float* __restrict__ h_in, const float* __restrict__ t,
                         const float* __restrict__ win_w, const float* __restrict__ win_b,
                         float* __restrict__ h)
{
    int node = blockIdx.x; int c = threadIdx.x;
    float in[6];
    #pragma unroll
    for (int k=0;k<FA_;k++) in[k] = h_in[node*FA_+k];
    in[5] = t[node];
    float acc = win_b[c];
    #pragma unroll
    for (int k=0;k<6;k++) acc += in[k]*win_w[k*H_+c];
    h[(size_t)node*H_+c] = acc;
}

__global__ void k_init_xa(const float* __restrict__ x_in, const int* __restrict__ eidx,
                          const float* __restrict__ emask, float* __restrict__ x, float* __restrict__ a)
{
    int gid = blockIdx.x*256 + threadIdx.x;
    if (gid < BN_*3) x[gid] = x_in[gid];
    if (gid < BE_) {
        int b = gid / E_;
        int ii = eidx[2*gid], jj = eidx[2*gid+1];
        const float* xi = x_in + (size_t)(b*N_+ii)*3;
        const float* xj = x_in + (size_t)(b*N_+jj)*3;
        float dx = xi[0]-xj[0], dy = xi[1]-xj[1], dz = xi[2]-xj[2];
        a[gid] = sqrtf(dx*dx+dy*dy+dz*dz) * emask[gid];
    }
}

// ---------------- W fragmentization: row-major [K=256][N=256] fp32 -> MFMA B-frag bf16 hi/lo ----------------
// Layout per (layer,pass): hi plane [ks(8)][ct(16)][lane(64)][8] (65536 bf16), lo plane at +65536.
// Fragment semantic: lane holds B[k = ks*32 + (lane>>4)*8 + j][col = ct*16 + (lane&15)], j=0..7.
__global__ void k_wprep(const float* __restrict__ xw2, const float* __restrict__ ew2,
                        ushort* __restrict__ WfU, ushort* __restrict__ WfM)
{
    int gid = blockIdx.x*256 + threadIdx.x;
    if (gid >= L_*2*8192) return;
    int lane = gid & 63;
    int rest = gid >> 6;
    int ct = rest & 15; rest >>= 4;
    int ks = rest & 7;  rest >>= 3;
    int p  = rest & 1;  int l = rest >> 1;
    const float* src = (p ? ew2 : xw2) + (size_t)l*H_*H_;
    ushort* dst = (p ? WfM : WfU) + (size_t)l*131072;
    int g = lane>>4, li = lane&15;
    int col = ct*16 + li;
    int kb  = ks*32 + g*8;
    size_t fo = ((size_t)(ks*16+ct)*64 + lane)*8;
    ushort* dh = dst + fo;
    ushort* dl = dst + 65536 + fo;
    #pragma unroll
    for (int j=0;j<8;j++){
        float v = src[(size_t)(kb+j)*H_ + col];
        ushort h = f2bf(v);
        dh[j] = h;
        dl[j] = f2bf(v - bf2f(h));
    }
}

// ---------------- generic tiled fp32 GEMM (node-side) ----------------
struct GArg { const float* A; const float* Bw; const float* bias; const float* add; const float* rmask; float* C; };
struct GArgs { GArg g[6]; };

template<int ACT>
__global__ __launch_bounds__(256)
void k_gemm64(GArgs args, int M, int Kdim)
{
    const GArg ga = args.g[blockIdx.z];
    __shared__ float As[16*68];
    __shared__ float Bs[16*68];
    const int tid = threadIdx.x;
    const int row0 = blockIdx.x*64;
    const int col0 = blockIdx.y*64;
    const int ty = tid>>4, tx = tid&15;
    const int am = tid>>2, ak = (tid&3)<<2;
    const int bk = tid>>4, bn = (tid&15)<<2;
    float acc[4][4] = {};
    const float* Ap = ga.A + (size_t)min(row0+am, M-1)*Kdim + ak;
    const float* Bp = ga.Bw + (size_t)bk*H_ + col0 + bn;
    for (int k0=0; k0<Kdim; k0+=16) {
        float4 av = *(const float4*)(Ap + k0);
        float4 bv = *(const float4*)(Bp + (size_t)k0*H_);
        __syncthreads();
        As[(ak+0)*68+am]=av.x; As[(ak+1)*68+am]=av.y; As[(ak+2)*68+am]=av.z; As[(ak+3)*68+am]=av.w;
        *(float4*)&Bs[bk*68+bn] = bv;
        __syncthreads();
        #pragma unroll
        for (int k=0;k<16;k++) {
            float4 a4 = *(const float4*)&As[k*68 + (ty<<2)];
            float4 b4 = *(const float4*)&Bs[k*68 + (tx<<2)];
            float aa[4]={a4.x,a4.y,a4.z,a4.w};
            float bb[4]={b4.x,b4.y,b4.z,b4.w};
            #pragma unroll
            for (int i=0;i<4;i++)
                #pragma unroll
                for (int j=0;j<4;j++)
                    acc[i][j] = fmaf(aa[i], bb[j], acc[i][j]);
        }
    }
    const int r0 = row0 + (ty<<2);
    const int c0 = col0 + (tx<<2);
    float4 bias4 = make_float4(0.f,0.f,0.f,0.f);
    if (ga.bias) bias4 = *(const float4*)(ga.bias + c0);
    #pragma unroll
    for (int i=0;i<4;i++) {
        int r = r0+i;
        if (r >= M) break;
        float v0=acc[i][0]+bias4.x, v1=acc[i][1]+bias4.y, v2=acc[i][2]+bias4.z, v3=acc[i][3]+bias4.w;
        if (ga.add) {
            float4 ad = *(const float4*)(ga.add + (size_t)r*H_ + c0);
            v0+=ad.x; v1+=ad.y; v2+=ad.z; v3+=ad.w;
        }
        if (ACT==1) { v0=siluf_(v0); v1=siluf_(v1); v2=siluf_(v2); v3=siluf_(v3); }
        if (ga.rmask) { float mv = ga.rmask[r]; v0*=mv; v1*=mv; v2*=mv; v3*=mv; }
        *(float4*)(ga.C + (size_t)r*H_ + c0) = make_float4(v0,v1,v2,v3);
    }
}

// ---------------- edge MLP layer-1 assembly (linear decomposition, geom fused) ----------------
// Emits u1/m1 directly as bf16 hi/lo planes (A-operand of the MFMA edge GEMM).
__global__ void k_edge_mlp1(const float* __restrict__ XHi, const float* __restrict__ XHj,
                            const float* __restrict__ EHi, const float* __restrict__ EHj,
                            const float* __restrict__ x, const float* __restrict__ a,
                            const int* __restrict__ eidx, const float* __restrict__ emask,
                            const float* __restrict__ xw512, const float* __restrict__ xw513, const float* __restrict__ xb1,
                            const float* __restrict__ ew512, const float* __restrict__ ew513, const float* __restrict__ eb1,
                            ushort* __restrict__ u1h, ushort* __restrict__ u1l,
                            ushort* __restrict__ m1h, ushort* __restrict__ m1l,
                            int e0, int ce)
{
    int gid = blockIdx.x*256+threadIdx.x;
    int le = gid>>6;
    if (le >= ce) return;
    int c4 = (gid&63)<<2;
    int ge = e0 + le;
    int b = ge / E_;
    int ii = eidx[2*ge], jj = eidx[2*ge+1];
    int ni = b*N_+ii, nj = b*N_+jj;
    size_t nio = (size_t)ni*H_ + c4;
    size_t njo = (size_t)nj*H_ + c4;
    float em = emask[ge];
    float dx=(x[ni*3+0]-x[nj*3+0])*em;
    float dy=(x[ni*3+1]-x[nj*3+1])*em;
    float dz=(x[ni*3+2]-x[nj*3+2])*em;
    float d2 = dx*dx+dy*dy+dz*dz;
    float av = a[ge];

    float4 xi = *(const float4*)(XHi+nio);
    float4 xj = *(const float4*)(XHj+njo);
    float4 w5 = *(const float4*)(xw512+c4);
    float4 w6 = *(const float4*)(xw513+c4);
    float4 bb = *(const float4*)(xb1+c4);
    float4 o;
    o.x = siluf_(xi.x+xj.x+d2*w5.x+av*w6.x+bb.x);
    o.y = siluf_(xi.y+xj.y+d2*w5.y+av*w6.y+bb.y);
    o.z = siluf_(xi.z+xj.z+d2*w5.z+av*w6.z+bb.z);
    o.w = siluf_(xi.w+xj.w+d2*w5.w+av*w6.w+bb.w);
    {
        ushort4 hh = make_ushort4(f2bf(o.x), f2bf(o.y), f2bf(o.z), f2bf(o.w));
        ushort4 ll = make_ushort4(f2bf(o.x-bf2f(hh.x)), f2bf(o.y-bf2f(hh.y)),
                                  f2bf(o.z-bf2f(hh.z)), f2bf(o.w-bf2f(hh.w)));
        *(ushort4*)(u1h + (size_t)le*H_ + c4) = hh;
        *(ushort4*)(u1l + (size_t)le*H_ + c4) = ll;
    }

    float4 ei = *(const float4*)(EHi+nio);
    float4 ej = *(const float4*)(EHj+njo);
    w5 = *(const float4*)(ew512+c4);
    w6 = *(const float4*)(ew513+c4);
    bb = *(const float4*)(eb1+c4);
    o.x = siluf_(ei.x+ej.x+d2*w5.x+av*w6.x+bb.x);
    o.y = siluf_(ei.y+ej.y+d2*w5.y+av*w6.y+bb.y);
    o.z = siluf_(ei.z+ej.z+d2*w5.z+av*w6.z+bb.z);
    o.w = siluf_(ei.w+ej.w+d2*w5.w+av*w6.w+bb.w);
    {
        ushort4 hh = make_ushort4(f2bf(o.x), f2bf(o.y), f2bf(o.z), f2bf(o.w));
        ushort4 ll = make_ushort4(f2bf(o.x-bf2f(hh.x)), f2bf(o.y-bf2f(hh.y)),
                                  f2bf(o.z-bf2f(hh.z)), f2bf(o.w-bf2f(hh.w)));
        *(ushort4*)(m1h + (size_t)le*H_ + c4) = hh;
        *(ushort4*)(m1l + (size_t)le*H_ + c4) = ll;
    }
}

// ---------------- MFMA mainloop: acc += A[128 rows x 256] @ W[256 x 256] (bf16x3) ----------------
// Per K-slice: 8 A-loads + two half-bursts of 8 B-loads each, all compile-time offsets,
// issued ahead of the dependent MFMAs so the compiler can pipeline loads under MFMA.
// Per-accumulator FMA chain order identical to the round-1 kernel (bit-identical results).
__device__ __forceinline__ void mfma_mainloop(
    const ushort* __restrict__ Ah, const ushort* __restrict__ Al,
    const ushort* __restrict__ Wf,
    const int arow[4], int g, int lane, int ch, f32x4 (&acc)[4][8])
{
    const ushort* apH[4]; const ushort* apL[4];
    #pragma unroll
    for (int rt=0; rt<4; ++rt){
        apH[rt] = Ah + (size_t)arow[rt]*H_ + g*8;
        apL[rt] = Al + (size_t)arow[rt]*H_ + g*8;
    }
    const ushort* bp = Wf + ((size_t)(ch*8)*64 + lane)*8;   // + ks*8192 + ct*512 (+65536 for lo)

    #pragma unroll
    for (int ks=0; ks<8; ++ks){
        bf16x8 ah[4], al[4];
        #pragma unroll
        for (int rt=0; rt<4; ++rt){
            ah[rt] = *(const bf16x8*)(apH[rt] + ks*32);
            al[rt] = *(const bf16x8*)(apL[rt] + ks*32);
        }
        #pragma unroll
        for (int half=0; half<2; ++half){
            bf16x8 bh[4], bl[4];
            #pragma unroll
            for (int q=0; q<4; ++q){
                const int ct = half*4 + q;
                bh[q] = *(const bf16x8*)(bp + ks*8192 + ct*512);
                bl[q] = *(const bf16x8*)(bp + 65536 + ks*8192 + ct*512);
            }
            #pragma unroll
            for (int q=0; q<4; ++q){
                const int ct = half*4 + q;
                #pragma unroll
                for (int rt=0; rt<4; ++rt){
                    acc[rt][ct] = __builtin_amdgcn_mfma_f32_16x16x32_bf16(ah[rt], bh[q], acc[rt][ct], 0,0,0);
                    acc[rt][ct] = __builtin_amdgcn_mfma_f32_16x16x32_bf16(al[rt], bh[q], acc[rt][ct], 0,0,0);
                    acc[rt][ct] = __builtin_amdgcn_mfma_f32_16x16x32_bf16(ah[rt], bl[q], acc[rt][ct], 0,0,0);
                }
            }
        }
    }
}

// ---------------- edge GEMM via MFMA bf16x3, fused silu + pd dot / M2 store ----------------
struct EArg2 { const ushort* Ah; const ushort* Al; const ushort* Wf;
               const float* b2; const float* wd; float* Mout; float* pd; };
struct EArgs2 { EArg2 g[2]; };

__global__ __launch_bounds__(256, 2)
void k_edge_gemm_mfma(EArgs2 args, int e0, int ce)
{
    const EArg2 ga = args.g[blockIdx.z];
    const int tid  = threadIdx.x;
    const int lane = tid & 63;
    const int w    = tid >> 6;
    const int rh   = w >> 1;      // row half (0/1) -> 64 rows
    const int ch   = w & 1;       // col half (0/1) -> 128 cols
    const int g    = lane >> 4;   // k-octet group / C row-quad group
    const int li   = lane & 15;   // A row within tile / C col within tile
    const int row0 = blockIdx.x*128;

    int arow[4];
    #pragma unroll
    for (int rt=0; rt<4; ++rt){
        int r = row0 + rh*64 + rt*16 + li;
        arow[rt] = (r < ce) ? r : (ce-1);
    }

    f32x4 acc[4][8];
    #pragma unroll
    for (int rt=0;rt<4;++rt)
        #pragma unroll
        for (int ct=0;ct<8;++ct)
            acc[rt][ct] = (f32x4){0.f,0.f,0.f,0.f};

    mfma_mainloop(ga.Ah, ga.Al, ga.Wf, arow, g, lane, ch, acc);

    // epilogue: v = silu(acc + bias); pd partial over this col-half; optional M2 store.
    float pdv[4][4];
    #pragma unroll
    for (int rt=0;rt<4;++rt)
        #pragma unroll
        for (int rg=0;rg<4;++rg) pdv[rt][rg] = 0.f;

    #pragma unroll
    for (int ct=0; ct<8; ++ct){
        const int col = ch*128 + ct*16 + li;
        const float bi = ga.b2[col];
        const float wv = ga.wd[col];
        #pragma unroll
        for (int rt=0; rt<4; ++rt){
            #pragma unroll
            for (int rg=0; rg<4; ++rg){
                float v = siluf_(acc[rt][ct][rg] + bi);
                pdv[rt][rg] += v*wv;
                if (ga.Mout){
                    int le = row0 + rh*64 + rt*16 + g*4 + rg;
                    if (le < ce) ga.Mout[(size_t)le*H_ + col] = v;
                }
            }
        }
    }

    #pragma unroll
    for (int rt=0;rt<4;++rt)
        #pragma unroll
        for (int rg=0;rg<4;++rg){
            float s = pdv[rt][rg];
            s += __shfl_xor(s, 1, 16);
            s += __shfl_xor(s, 2, 16);
            s += __shfl_xor(s, 4, 16);
            s += __shfl_xor(s, 8, 16);
            pdv[rt][rg] = s;
        }

    if (li == 0){
        #pragma unroll
        for (int rt=0;rt<4;++rt){
            int le = row0 + rh*64 + rt*16 + g*4;
            if (le+3 < ce){
                *(float4*)(ga.pd + (size_t)ch*BE_ + e0 + le) =
                    make_float4(pdv[rt][0], pdv[rt][1], pdv[rt][2], pdv[rt][3]);
            } else {
                #pragma unroll
                for (int rg=0;rg<4;++rg)
                    if (le+rg < ce) ga.pd[(size_t)ch*BE_ + e0 + le + rg] = pdv[rt][rg];
            }
        }
    }
}

// ---------------- fused scatter: combine pd halves, x update, agg ----------------
__global__ void k_scatter2(const float* __restrict__ M2, const float* __restrict__ pdU, const float* __restrict__ pdM,
                           const float* __restrict__ attb,
                           const float* __restrict__ x_cur, float* __restrict__ x_new,
                           const int* __restrict__ eidx, const float* __restrict__ emask,
                           const float* __restrict__ nmask,
                           float* __restrict__ agg, int g0, int e0)
{
    int g = g0 + blockIdx.x;
    int b = g / N_, i = g - b*N_;
    int ge0 = b*E_ + i*DEG_;
    int le0 = ge0 - e0;
    int t = threadIdx.x;
    __shared__ float eas[DEG_];
    int drow = b*N_ + eidx[2*ge0];
    if (t < 64) {
        float cx=0.f, cy=0.f, cz=0.f;
        if (t < DEG_) {
            int ge = ge0 + t;
            float tsc = tanhf(pdU[ge] + pdU[BE_+ge])*SCALE_;
            float ea  = sigmoidf_(pdM[ge] + pdM[BE_+ge] + attb[0]);
            eas[t] = ea;
            int ii = eidx[2*ge], jj = eidx[2*ge+1];
            int ni = b*N_+ii, nj = b*N_+jj;
            float em = emask[ge];
            float dx=(x_cur[ni*3+0]-x_cur[nj*3+0])*em;
            float dy=(x_cur[ni*3+1]-x_cur[nj*3+1])*em;
            float dz=(x_cur[ni*3+2]-x_cur[nj*3+2])*em;
            float dd = sqrtf(dx*dx+dy*dy+dz*dz);
            float sc = tsc/(dd+1.0f);
            cx=sc*dx; cy=sc*dy; cz=sc*dz;
        }
        #pragma unroll
        for (int off=32; off; off>>=1) {
            cx+=__shfl_xor(cx,off,64); cy+=__shfl_xor(cy,off,64); cz+=__shfl_xor(cz,off,64);
        }
        if (t==0) {
            float nm = nmask[drow];
            x_new[drow*3+0]=(x_cur[drow*3+0]+cx)*nm;
            x_new[drow*3+1]=(x_cur[drow*3+1]+cy)*nm;
            x_new[drow*3+2]=(x_cur[drow*3+2]+cz)*nm;
        }
    }
    __syncthreads();
    float s=0.f;
    #pragma unroll 4
    for (int k=0;k<DEG_;k++) s += eas[k]*M2[(size_t)(le0+k)*H_ + t];
    agg[(size_t)drow*H_ + t] = s;
}

// ---------------- outputs ----------------
__global__ void k_out_x(const float* __restrict__ x, const float* __restrict__ x_in,
                        const float* __restrict__ nmask, float* __restrict__ out)
{
    int b = blockIdx.x; int l = threadIdx.x;
    int row = b*N_ + l;
    float xd0=0.f,xd1=0.f,xd2=0.f,nm=0.f;
    if (l < N_) {
        nm = nmask[row];
        xd0 = (x[(size_t)row*3+0]-x_in[(size_t)row*3+0])*nm;
        xd1 = (x[(size_t)row*3+1]-x_in[(size_t)row*3+1])*nm;
        xd2 = (x[(size_t)row*3+2]-x_in[(size_t)row*3+2])*nm;
    }
    float s0=xd0,s1=xd1,s2=xd2,sn=nm;
    #pragma unroll
    for (int off=32; off; off>>=1) {
        s0+=__shfl_xor(s0,off,64); s1+=__shfl_xor(s1,off,64);
        s2+=__shfl_xor(s2,off,64); sn+=__shfl_xor(sn,off,64);
    }
    float m0=s0/sn, m1=s1/sn, m2=s2/sn;
    if (l < N_) {
        out[(size_t)row*8+0]=(xd0-m0)*nm;
        out[(size_t)row*8+1]=(xd1-m1)*nm;
        out[(size_t)row*8+2]=(xd2-m2)*nm;
    }
}

__global__ void k_out_h(const float* __restrict__ h, const float* __restrict__ wout_w, const float* __restrict__ wout_b,
                        const float* __restrict__ nmask, float* __restrict__ out)
{
    int row = blockIdx.x; int lane = threadIdx.x;
    int c4 = lane<<2;
    float4 hv = *(const float4*)(h + (size_t)row*H_ + c4);
    float p0=0,p1=0,p2=0,p3=0,p4=0;
    float hvv[4] = {hv.x,hv.y,hv.z,hv.w};
    #pragma unroll
    for (int j=0;j<4;j++) {
        int k = c4+j;
        float hval = hvv[j];
        p0 += hval * wout_w[k*6+0];
        p1 += hval * wout_w[k*6+1];
        p2 += hval * wout_w[k*6+2];
        p3 += hval * wout_w[k*6+3];
        p4 += hval * wout_w[k*6+4];
    }
    #pragma unroll
    for (int off=32; off; off>>=1) {
        p0+=__shfl_xor(p0,off,64); p1+=__shfl_xor(p1,off,64); p2+=__shfl_xor(p2,off,64);
        p3+=__shfl_xor(p3,off,64); p4+=__shfl_xor(p4,off,64);
    }
    if (lane==0) {
        float nm = nmask[row];
        out[(size_t)row*8+3] = (p0+wout_b[0])*nm;
        out[(size_t)row*8+4] = (p1+wout_b[1])*nm;
        out[(size_t)row*8+5] = (p2+wout_b[2])*nm;
        out[(size_t)row*8+6] = (p3+wout_b[3])*nm;
        out[(size_t)row*8+7] = (p4+wout_b[4])*nm;
    }
}

extern "C" void kernel_launch(void* const* d_in, const int* in_sizes, int n_in,
                              void* d_out, int out_size, void* d_ws, size_t ws_size,
                              hipStream_t stream)
{
    const float* x_in  = (const float*)d_in[0];
    const float* h_in  = (const float*)d_in[1];
    const float* t     = (const float*)d_in[2];
    const float* nmask = (const float*)d_in[3];
    const float* emask = (const float*)d_in[4];
    const int*   eidx  = (const int*)d_in[5];
    const float* win_w = (const float*)d_in[6];
    const float* win_b = (const float*)d_in[7];
    const float* wout_w= (const float*)d_in[8];
    const float* wout_b= (const float*)d_in[9];
    const float* e_w1  = (const float*)d_in[10];
    const float* e_b1  = (const float*)d_in[11];
    const float* e_w2  = (const float*)d_in[12];
    const float* e_b2  = (const float*)d_in[13];
    const float* att_w = (const float*)d_in[14];
    const float* att_b = (const float*)d_in[15];
    const float* h_w1  = (const float*)d_in[16];
    const float* h_b1  = (const float*)d_in[17];
    const float* h_w2  = (const float*)d_in[18];
    const float* h_b2  = (const float*)d_in[19];
    const float* x_w1  = (const float*)d_in[20];
    const float* x_b1  = (const float*)d_in[21];
    const float* x_w2  = (const float*)d_in[22];
    const float* x_b2  = (const float*)d_in[23];
    const float* x_w3  = (const float*)d_in[24];
    float* out = (float*)d_out;

    char* ws = (char*)d_ws;
    size_t off = 0;
    auto alloc = [&](size_t bytes)->float* {
        float* p = (float*)(ws + off);
        off = (off + bytes + 255) & ~(size_t)255;
        return p;
    };
    float* h    = alloc((size_t)BN_*H_*4);
    float* xA   = alloc((size_t)BN_*3*4);
    float* xB   = alloc((size_t)BN_*3*4);
    float* a    = alloc((size_t)BE_*4);
    float* pdU  = alloc((size_t)2*BE_*4);
    float* pdM  = alloc((size_t)2*BE_*4);
    float* NB5  = alloc((size_t)5*BN_*H_*4);
    float* agg  = alloc((size_t)BN_*H_*4);
    float* hm1  = alloc((size_t)BN_*H_*4);
    // fragmentized W (bf16 hi/lo), all layers, both passes: L * 131072 ushorts each
    ushort* WfU = (ushort*)alloc((size_t)L_*131072*sizeof(ushort));
    ushort* WfM = (ushort*)alloc((size_t)L_*131072*sizeof(ushort));

    // chunk the big edge activation buffers (u1,m1 bf16 hi/lo planes; M2 fp32) to fit ws_size
    size_t avail = (ws_size > off) ? (ws_size - off) : 0;
    long ce_cap = (long)(avail / ((size_t)3*H_*4));
    long gcap = ce_cap / DEG_;
    if (gcap < 1) gcap = 1;
    if (gcap > BN_) gcap = BN_;
    int nc  = (int)((BN_ + gcap - 1)/gcap);
    int gpc = (BN_ + nc - 1)/nc;
    int cecap = gpc*DEG_;
    float* u1 = alloc((size_t)cecap*H_*4);   // = 2 bf16 planes (hi, lo)
    float* m1 = alloc((size_t)cecap*H_*4);
    float* M2 = alloc((size_t)cecap*H_*4);
    ushort* u1h = (ushort*)u1;
    ushort* u1l = u1h + (size_t)cecap*H_;
    ushort* m1h = (ushort*)m1;
    ushort* m1l = m1h + (size_t)cecap*H_;

    k_init_h<<<BN_, H_, 0, stream>>>(h_in, t, win_w, win_b, h);
    k_init_xa<<<(BE_+255)/256, 256, 0, stream>>>(x_in, eidx, emask, xA, a);
    k_wprep<<<(L_*2*8192+255)/256, 256, 0, stream>>>(x_w2, e_w2, WfU, WfM);

    float* x_cur = xA;
    float* x_new = xB;

    for (int l=0; l<L_; l++) {
        const float* xw1l = x_w1 + (size_t)l*514*H_;
        const float* ew1l = e_w1 + (size_t)l*514*H_;
        const float* hw1l = h_w1 + (size_t)l*512*H_;

        // 5 node-side GEMMs sharing A=h: XHi, XHj, EHi, EHj, Htop
        GArgs na = {};
        const float* Bz[5] = { xw1l, xw1l+(size_t)256*H_, ew1l, ew1l+(size_t)256*H_, hw1l };
        for (int z=0;z<5;z++){
            na.g[z].A=h; na.g[z].Bw=Bz[z]; na.g[z].bias=nullptr; na.g[z].add=nullptr;
            na.g[z].rmask=nullptr; na.g[z].C=NB5 + (size_t)z*BN_*H_;
        }
        k_gemm64<0><<<dim3(BN_/64, H_/64, 5),256,0,stream>>>(na, BN_, H_);

        float* XHi=NB5;
        float* XHj=NB5+(size_t)BN_*H_;
        float* EHi=NB5+(size_t)2*BN_*H_;
        float* EHj=NB5+(size_t)3*BN_*H_;
        float* Htop=NB5+(size_t)4*BN_*H_;

        for (int c=0;c<nc;c++) {
            int g0 = c*gpc;
            int g1 = (g0+gpc < BN_) ? (g0+gpc) : BN_;
            int ng = g1-g0;
            if (ng <= 0) break;
            int e0 = g0*DEG_; int ce = ng*DEG_;

            k_edge_mlp1<<<(ce*64+255)/256,256,0,stream>>>(XHi,XHj,EHi,EHj, x_cur, a, eidx, emask,
                xw1l+(size_t)512*H_, xw1l+(size_t)513*H_, x_b1+(size_t)l*H_,
                ew1l+(size_t)512*H_, ew1l+(size_t)513*H_, e_b1+(size_t)l*H_,
                u1h, u1l, m1h, m1l, e0, ce);

            EArgs2 ea = {};
            ea.g[0] = { u1h, u1l, WfU + (size_t)l*131072, x_b2+(size_t)l*H_, x_w3+(size_t)l*H_,  nullptr, pdU };
            ea.g[1] = { m1h, m1l, WfM + (size_t)l*131072, e_b2+(size_t)l*H_, att_w+(size_t)l*H_, M2,      pdM };
            k_edge_gemm_mfma<<<dim3((ce+127)/128, 1, 2),256,0,stream>>>(ea, e0, ce);

            k_scatter2<<<ng,256,0,stream>>>(M2, pdU, pdM, att_b+l, x_cur, x_new,
                                            eidx, emask, nmask, agg, g0, e0);
        }

        GArgs ha = {};
        ha.g[0] = { agg, hw1l+(size_t)256*H_, h_b1+(size_t)l*H_, Htop, nullptr, hm1 };
        k_gemm64<1><<<dim3(BN_/64,H_/64,1),256,0,stream>>>(ha, BN_, H_);

        GArgs h2 = {};
        h2.g[0] = { hm1, h_w2+(size_t)l*H_*H_, h_b2+(size_t)l*H_, h, nmask, h };
        k_gemm64<0><<<dim3(BN_/64,H_/64,1),256,0,stream>>>(h2, BN_, H_);

        float* tmp = x_cur; x_cur = x_new; x_new = tmp;
    }

    k_out_x<<<B_,64,0,stream>>>(x_cur, x_in, nmask, out);
    k_out_h<<<BN_,64,0,stream>>>(h, wout_w, wout_b, nmask, out);
}

// Round 5
// 1572.909 us; speedup vs baseline: 1.1046x; 1.1046x over previous
//
#include <hip/hip_runtime.h>
#include <math.h>

#define B_ 64
#define N_ 29
#define E_ 812
#define L_ 9
#define H_ 256
#define FA_ 5
#define BN_ (B_*N_)   // 1856
#define BE_ (B_*E_)   // 51968
#define DEG_ 28
#define SCALE_ 15.0f

typedef __attribute__((ext_vector_type(8))) short bf16x8;
typedef __attribute__((ext_vector_type(4))) float f32x4;

__device__ __forceinline__ float sigmoidf_(float v){ return 1.0f/(1.0f+expf(-v)); }
__device__ __forceinline__ float siluf_(float v){ return v/(1.0f+expf(-v)); }

// bf16 round-to-nearest-even conversion + back
__device__ __forceinline__ ushort f2bf(float f){
    uint u = __float_as_uint(f);
    u += 0x7fffu + ((u>>16)&1u);
    return (ushort)(u>>16);
}
__device__ __forceinline__ float bf2f(ushort h){ return __uint_as_float(((uint)h)<<16); }

// ---------------- init ----------------
__global__ void k_init_h(const float* __restrict__ h_in, const float* __restrict__ t,
                         const float* __restrict__ win_w, const float* __restrict__ win_b,
                         float* __restrict__ h)
{
    int node = blockIdx.x; int c = threadIdx.x;
    float in[6];
    #pragma unroll
    for (int k=0;k<FA_;k++) in[k] = h_in[node*FA_+k];
    in[5] = t[node];
    float acc = win_b[c];
    #pragma unroll
    for (int k=0;k<6;k++) acc += in[k]*win_w[k*H_+c];
    h[(size_t)node*H_+c] = acc;
}

__global__ void k_init_xa(const float* __restrict__ x_in, const int* __restrict__ eidx,
                          const float* __restrict__ emask, float* __restrict__ x, float* __restrict__ a)
{
    int gid = blockIdx.x*256 + threadIdx.x;
    if (gid < BN_*3) x[gid] = x_in[gid];
    if (gid < BE_) {
        int b = gid / E_;
        int ii = eidx[2*gid], jj = eidx[2*gid+1];
        const float* xi = x_in + (size_t)(b*N_+ii)*3;
        const float* xj = x_in + (size_t)(b*N_+jj)*3;
        float dx = xi[0]-xj[0], dy = xi[1]-xj[1], dz = xi[2]-xj[2];
        a[gid] = sqrtf(dx*dx+dy*dy+dz*dz) * emask[gid];
    }
}

// ---------------- W fragmentization: row-major [K=256][N=256] fp32 -> MFMA B-frag bf16 hi/lo ----------------
// Layout per (layer,pass): hi plane [ks(8)][ct(16)][lane(64)][8] (65536 bf16), lo plane at +65536.
// Fragment semantic: lane holds B[k = ks*32 + (lane>>4)*8 + j][col = ct*16 + (lane&15)], j=0..7.
__global__ void k_wprep(const float* __restrict__ xw2, const float* __restrict__ ew2,
                        ushort* __restrict__ WfU, ushort* __restrict__ WfM)
{
    int gid = blockIdx.x*256 + threadIdx.x;
    if (gid >= L_*2*8192) return;
    int lane = gid & 63;
    int rest = gid >> 6;
    int ct = rest & 15; rest >>= 4;
    int ks = rest & 7;  rest >>= 3;
    int p  = rest & 1;  int l = rest >> 1;
    const float* src = (p ? ew2 : xw2) + (size_t)l*H_*H_;
    ushort* dst = (p ? WfM : WfU) + (size_t)l*131072;
    int g = lane>>4, li = lane&15;
    int col = ct*16 + li;
    int kb  = ks*32 + g*8;
    size_t fo = ((size_t)(ks*16+ct)*64 + lane)*8;
    ushort* dh = dst + fo;
    ushort* dl = dst + 65536 + fo;
    #pragma unroll
    for (int j=0;j<8;j++){
        float v = src[(size_t)(kb+j)*H_ + col];
        ushort h = f2bf(v);
        dh[j] = h;
        dl[j] = f2bf(v - bf2f(h));
    }
}

// ---------------- generic tiled fp32 GEMM (node-side) ----------------
struct GArg { const float* A; const float* Bw; const float* bias; const float* add; const float* rmask; float* C; };
struct GArgs { GArg g[6]; };

template<int ACT>
__global__ __launch_bounds__(256)
void k_gemm64(GArgs args, int M, int Kdim)
{
    const GArg ga = args.g[blockIdx.z];
    __shared__ float As[16*68];
    __shared__ float Bs[16*68];
    const int tid = threadIdx.x;
    const int row0 = blockIdx.x*64;
    const int col0 = blockIdx.y*64;
    const int ty = tid>>4, tx = tid&15;
    const int am = tid>>2, ak = (tid&3)<<2;
    const int bk = tid>>4, bn = (tid&15)<<2;
    float acc[4][4] = {};
    const float* Ap = ga.A + (size_t)min(row0+am, M-1)*Kdim + ak;
    const float* Bp = ga.Bw + (size_t)bk*H_ + col0 + bn;
    for (int k0=0; k0<Kdim; k0+=16) {
        float4 av = *(const float4*)(Ap + k0);
        float4 bv = *(const float4*)(Bp + (size_t)k0*H_);
        __syncthreads();
        As[(ak+0)*68+am]=av.x; As[(ak+1)*68+am]=av.y; As[(ak+2)*68+am]=av.z; As[(ak+3)*68+am]=av.w;
        *(float4*)&Bs[bk*68+bn] = bv;
        __syncthreads();
        #pragma unroll
        for (int k=0;k<16;k++) {
            float4 a4 = *(const float4*)&As[k*68 + (ty<<2)];
            float4 b4 = *(const float4*)&Bs[k*68 + (tx<<2)];
            float aa[4]={a4.x,a4.y,a4.z,a4.w};
            float bb[4]={b4.x,b4.y,b4.z,b4.w};
            #pragma unroll
            for (int i=0;i<4;i++)
                #pragma unroll
                for (int j=0;j<4;j++)
                    acc[i][j] = fmaf(aa[i], bb[j], acc[i][j]);
        }
    }
    const int r0 = row0 + (ty<<2);
    const int c0 = col0 + (tx<<2);
    float4 bias4 = make_float4(0.f,0.f,0.f,0.f);
    if (ga.bias) bias4 = *(const float4*)(ga.bias + c0);
    #pragma unroll
    for (int i=0;i<4;i++) {
        int r = r0+i;
        if (r >= M) break;
        float v0=acc[i][0]+bias4.x, v1=acc[i][1]+bias4.y, v2=acc[i][2]+bias4.z, v3=acc[i][3]+bias4.w;
        if (ga.add) {
            float4 ad = *(const float4*)(ga.add + (size_t)r*H_ + c0);
            v0+=ad.x; v1+=ad.y; v2+=ad.z; v3+=ad.w;
        }
        if (ACT==1) { v0=siluf_(v0); v1=siluf_(v1); v2=siluf_(v2); v3=siluf_(v3); }
        if (ga.rmask) { float mv = ga.rmask[r]; v0*=mv; v1*=mv; v2*=mv; v3*=mv; }
        *(float4*)(ga.C + (size_t)r*H_ + c0) = make_float4(v0,v1,v2,v3);
    }
}

// ---------------- edge MLP layer-1 assembly, emits A-planes in MFMA FRAGMENT order ----------------
// Plane layout (per hi/lo plane): [rb(64-row band)][ks(8)][rt(4)][lane(64)][8] ushorts.
// Fragment: lane(g=lane>>4, li=lane&15) holds A[row = rb*64+rt*16+li][k = ks*32+g*8+j], j=0..7.
// One thread computes one fragment slot (8 k-values) for BOTH u1 and m1.
__global__ void k_edge_mlp1(const float* __restrict__ XHi, const float* __restrict__ XHj,
                            const float* __restrict__ EHi, const float* __restrict__ EHj,
                            const float* __restrict__ x, const float* __restrict__ a,
                            const int* __restrict__ eidx, const float* __restrict__ emask,
                            const float* __restrict__ xw512, const float* __restrict__ xw513, const float* __restrict__ xb1,
                            const float* __restrict__ ew512, const float* __restrict__ ew513, const float* __restrict__ eb1,
                            ushort* __restrict__ u1h, ushort* __restrict__ u1l,
                            ushort* __restrict__ m1h, ushort* __restrict__ m1l,
                            int e0, int ce, int nrb)
{
    int gid = blockIdx.x*256 + threadIdx.x;
    if (gid >= nrb*2048) return;
    int lane = gid & 63;
    int rest = gid >> 6;
    int rt = rest & 3; rest >>= 2;
    int ks = rest & 7; rest >>= 3;
    int rb = rest;
    int li = lane & 15, g = lane >> 4;
    int row = rb*64 + rt*16 + li;
    int kb  = ks*32 + g*8;
    size_t fo = ((size_t)((rb*8+ks)*4+rt)*64 + lane)*8;

    if (row >= ce) {
        ushort4 z4 = make_ushort4(0,0,0,0);
        *(ushort4*)(u1h+fo)=z4; *(ushort4*)(u1h+fo+4)=z4;
        *(ushort4*)(u1l+fo)=z4; *(ushort4*)(u1l+fo+4)=z4;
        *(ushort4*)(m1h+fo)=z4; *(ushort4*)(m1h+fo+4)=z4;
        *(ushort4*)(m1l+fo)=z4; *(ushort4*)(m1l+fo+4)=z4;
        return;
    }

    int ge = e0 + row;
    int b = ge / E_;
    int ii = eidx[2*ge], jj = eidx[2*ge+1];
    int ni = b*N_+ii, nj = b*N_+jj;
    float em = emask[ge];
    float dx=(x[ni*3+0]-x[nj*3+0])*em;
    float dy=(x[ni*3+1]-x[nj*3+1])*em;
    float dz=(x[ni*3+2]-x[nj*3+2])*em;
    float d2 = dx*dx+dy*dy+dz*dz;
    float av = a[ge];
    size_t nio = (size_t)ni*H_ + kb;
    size_t njo = (size_t)nj*H_ + kb;

    // --- u1 (x-path) ---
    {
        float4 i0 = *(const float4*)(XHi+nio),   i1 = *(const float4*)(XHi+nio+4);
        float4 j0 = *(const float4*)(XHj+njo),   j1 = *(const float4*)(XHj+njo+4);
        float4 w50= *(const float4*)(xw512+kb),  w51= *(const float4*)(xw512+kb+4);
        float4 w60= *(const float4*)(xw513+kb),  w61= *(const float4*)(xw513+kb+4);
        float4 b0 = *(const float4*)(xb1+kb),    b1v= *(const float4*)(xb1+kb+4);
        float v[8];
        v[0]=siluf_(i0.x+j0.x+d2*w50.x+av*w60.x+b0.x);
        v[1]=siluf_(i0.y+j0.y+d2*w50.y+av*w60.y+b0.y);
        v[2]=siluf_(i0.z+j0.z+d2*w50.z+av*w60.z+b0.z);
        v[3]=siluf_(i0.w+j0.w+d2*w50.w+av*w60.w+b0.w);
        v[4]=siluf_(i1.x+j1.x+d2*w51.x+av*w61.x+b1v.x);
        v[5]=siluf_(i1.y+j1.y+d2*w51.y+av*w61.y+b1v.y);
        v[6]=siluf_(i1.z+j1.z+d2*w51.z+av*w61.z+b1v.z);
        v[7]=siluf_(i1.w+j1.w+d2*w51.w+av*w61.w+b1v.w);
        ushort hh[8], ll[8];
        #pragma unroll
        for (int q=0;q<8;q++){ hh[q]=f2bf(v[q]); ll[q]=f2bf(v[q]-bf2f(hh[q])); }
        *(ushort4*)(u1h+fo)   = make_ushort4(hh[0],hh[1],hh[2],hh[3]);
        *(ushort4*)(u1h+fo+4) = make_ushort4(hh[4],hh[5],hh[6],hh[7]);
        *(ushort4*)(u1l+fo)   = make_ushort4(ll[0],ll[1],ll[2],ll[3]);
        *(ushort4*)(u1l+fo+4) = make_ushort4(ll[4],ll[5],ll[6],ll[7]);
    }
    // --- m1 (h-path) ---
    {
        float4 i0 = *(const float4*)(EHi+nio),   i1 = *(const float4*)(EHi+nio+4);
        float4 j0 = *(const float4*)(EHj+njo),   j1 = *(const float4*)(EHj+njo+4);
        float4 w50= *(const float4*)(ew512+kb),  w51= *(const float4*)(ew512+kb+4);
        float4 w60= *(const float4*)(ew513+kb),  w61= *(const float4*)(ew513+kb+4);
        float4 b0 = *(const float4*)(eb1+kb),    b1v= *(const float4*)(eb1+kb+4);
        float v[8];
        v[0]=siluf_(i0.x+j0.x+d2*w50.x+av*w60.x+b0.x);
        v[1]=siluf_(i0.y+j0.y+d2*w50.y+av*w60.y+b0.y);
        v[2]=siluf_(i0.z+j0.z+d2*w50.z+av*w60.z+b0.z);
        v[3]=siluf_(i0.w+j0.w+d2*w50.w+av*w60.w+b0.w);
        v[4]=siluf_(i1.x+j1.x+d2*w51.x+av*w61.x+b1v.x);
        v[5]=siluf_(i1.y+j1.y+d2*w51.y+av*w61.y+b1v.y);
        v[6]=siluf_(i1.z+j1.z+d2*w51.z+av*w61.z+b1v.z);
        v[7]=siluf_(i1.w+j1.w+d2*w51.w+av*w61.w+b1v.w);
        ushort hh[8], ll[8];
        #pragma unroll
        for (int q=0;q<8;q++){ hh[q]=f2bf(v[q]); ll[q]=f2bf(v[q]-bf2f(hh[q])); }
        *(ushort4*)(m1h+fo)   = make_ushort4(hh[0],hh[1],hh[2],hh[3]);
        *(ushort4*)(m1h+fo+4) = make_ushort4(hh[4],hh[5],hh[6],hh[7]);
        *(ushort4*)(m1l+fo)   = make_ushort4(ll[0],ll[1],ll[2],ll[3]);
        *(ushort4*)(m1l+fo+4) = make_ushort4(ll[4],ll[5],ll[6],ll[7]);
    }
}

// ---------------- edge GEMM via MFMA bf16x3: block = 64 rows x 256 cols, 4 waves (col quarters) ----------------
// A planes fragment-ordered (see k_edge_mlp1) -> every A load is a coalesced 1KB wave transaction.
// acc[4][4] = 64 AGPR/wave; __launch_bounds__(256,4) caps VGPR at 128 -> 4 waves/SIMD.
// pd written per col-quarter plane: pd[ch*BE_ + e0 + row].
struct EArg2 { const ushort* Ah; const ushort* Al; const ushort* Wf;
               const float* b2; const float* wd; float* Mout; float* pd; };
struct EArgs2 { EArg2 g[2]; };

__global__ __launch_bounds__(256, 4)
void k_edge_gemm_mfma(EArgs2 args, int e0, int ce)
{
    const EArg2 ga = args.g[blockIdx.z];
    const int tid  = threadIdx.x;
    const int lane = tid & 63;
    const int ch   = tid >> 6;    // col quarter (0..3) -> 64 cols
    const int g    = lane >> 4;   // k-octet group / C row-quad group
    const int li   = lane & 15;   // A row within tile / C col within tile
    const int rb   = blockIdx.x;
    const int row0 = rb*64;

    f32x4 acc[4][4];
    #pragma unroll
    for (int rt=0;rt<4;++rt)
        #pragma unroll
        for (int ct=0;ct<4;++ct)
            acc[rt][ct] = (f32x4){0.f,0.f,0.f,0.f};

    const ushort* ap  = ga.Ah + (size_t)rb*16384 + (size_t)lane*8;
    const ushort* alp = ga.Al + (size_t)rb*16384 + (size_t)lane*8;
    const ushort* bp  = ga.Wf + ((size_t)(ch*4)*64 + lane)*8;  // + ks*8192 + ct*512 (+65536 lo)

    #pragma unroll
    for (int ks=0; ks<8; ++ks){
        bf16x8 ah[4], al[4];
        #pragma unroll
        for (int rt=0; rt<4; ++rt){
            ah[rt] = *(const bf16x8*)(ap  + (ks*4+rt)*512);
            al[rt] = *(const bf16x8*)(alp + (ks*4+rt)*512);
        }
        #pragma unroll
        for (int ct=0; ct<4; ++ct){
            bf16x8 bh = *(const bf16x8*)(bp + ks*8192 + ct*512);
            bf16x8 bl = *(const bf16x8*)(bp + 65536 + ks*8192 + ct*512);
            #pragma unroll
            for (int rt=0; rt<4; ++rt){
                acc[rt][ct] = __builtin_amdgcn_mfma_f32_16x16x32_bf16(ah[rt], bh, acc[rt][ct], 0,0,0);
                acc[rt][ct] = __builtin_amdgcn_mfma_f32_16x16x32_bf16(al[rt], bh, acc[rt][ct], 0,0,0);
                acc[rt][ct] = __builtin_amdgcn_mfma_f32_16x16x32_bf16(ah[rt], bl, acc[rt][ct], 0,0,0);
            }
        }
    }

    // epilogue: v = silu(acc + bias); pd partial over this col-quarter; optional M2 store.
    float pdv[4][4];
    #pragma unroll
    for (int rt=0;rt<4;++rt)
        #pragma unroll
        for (int rg=0;rg<4;++rg) pdv[rt][rg] = 0.f;

    #pragma unroll
    for (int ct=0; ct<4; ++ct){
        const int col = ch*64 + ct*16 + li;
        const float bi = ga.b2[col];
        const float wv = ga.wd[col];
        #pragma unroll
        for (int rt=0; rt<4; ++rt){
            #pragma unroll
            for (int rg=0; rg<4; ++rg){
                float v = siluf_(acc[rt][ct][rg] + bi);
                pdv[rt][rg] += v*wv;
                if (ga.Mout){
                    int le = row0 + rt*16 + g*4 + rg;
                    if (le < ce) ga.Mout[(size_t)le*H_ + col] = v;
                }
            }
        }
    }

    #pragma unroll
    for (int rt=0;rt<4;++rt)
        #pragma unroll
        for (int rg=0;rg<4;++rg){
            float s = pdv[rt][rg];
            s += __shfl_xor(s, 1, 16);
            s += __shfl_xor(s, 2, 16);
            s += __shfl_xor(s, 4, 16);
            s += __shfl_xor(s, 8, 16);
            pdv[rt][rg] = s;
        }

    if (li == 0){
        #pragma unroll
        for (int rt=0;rt<4;++rt){
            int le = row0 + rt*16 + g*4;
            if (le+3 < ce){
                *(float4*)(ga.pd + (size_t)ch*BE_ + e0 + le) =
                    make_float4(pdv[rt][0], pdv[rt][1], pdv[rt][2], pdv[rt][3]);
            } else {
                #pragma unroll
                for (int rg=0;rg<4;++rg)
                    if (le+rg < ce) ga.pd[(size_t)ch*BE_ + e0 + le + rg] = pdv[rt][rg];
            }
        }
    }
}

// ---------------- fused scatter: combine 4 pd quarters, x update, agg ----------------
__global__ void k_scatter2(const float* __restrict__ M2, const float* __restrict__ pdU, const float* __restrict__ pdM,
                           const float* __restrict__ attb,
                           const float* __restrict__ x_cur, float* __restrict__ x_new,
                           const int* __restrict__ eidx, const float* __restrict__ emask,
                           const float* __restrict__ nmask,
                           float* __restrict__ agg, int g0, int e0)
{
    int g = g0 + blockIdx.x;
    int b = g / N_, i = g - b*N_;
    int ge0 = b*E_ + i*DEG_;
    int le0 = ge0 - e0;
    int t = threadIdx.x;
    __shared__ float eas[DEG_];
    int drow = b*N_ + eidx[2*ge0];
    if (t < 64) {
        float cx=0.f, cy=0.f, cz=0.f;
        if (t < DEG_) {
            int ge = ge0 + t;
            float su = pdU[ge] + pdU[BE_+ge] + pdU[2*(size_t)BE_+ge] + pdU[3*(size_t)BE_+ge];
            float sm = pdM[ge] + pdM[BE_+ge] + pdM[2*(size_t)BE_+ge] + pdM[3*(size_t)BE_+ge];
            float tsc = tanhf(su)*SCALE_;
            float ea  = sigmoidf_(sm + attb[0]);
            eas[t] = ea;
            int ii = eidx[2*ge], jj = eidx[2*ge+1];
            int ni = b*N_+ii, nj = b*N_+jj;
            float em = emask[ge];
            float dx=(x_cur[ni*3+0]-x_cur[nj*3+0])*em;
            float dy=(x_cur[ni*3+1]-x_cur[nj*3+1])*em;
            float dz=(x_cur[ni*3+2]-x_cur[nj*3+2])*em;
            float dd = sqrtf(dx*dx+dy*dy+dz*dz);
            float sc = tsc/(dd+1.0f);
            cx=sc*dx; cy=sc*dy; cz=sc*dz;
        }
        #pragma unroll
        for (int off=32; off; off>>=1) {
            cx+=__shfl_xor(cx,off,64); cy+=__shfl_xor(cy,off,64); cz+=__shfl_xor(cz,off,64);
        }
        if (t==0) {
            float nm = nmask[drow];
            x_new[drow*3+0]=(x_cur[drow*3+0]+cx)*nm;
            x_new[drow*3+1]=(x_cur[drow*3+1]+cy)*nm;
            x_new[drow*3+2]=(x_cur[drow*3+2]+cz)*nm;
        }
    }
    __syncthreads();
    float s=0.f;
    #pragma unroll 4
    for (int k=0;k<DEG_;k++) s += eas[k]*M2[(size_t)(le0+k)*H_ + t];
    agg[(size_t)drow*H_ + t] = s;
}

// ---------------- outputs ----------------
__global__ void k_out_x(const float* __restrict__ x, const float* __restrict__ x_in,
                        const float* __restrict__ nmask, float* __restrict__ out)
{
    int b = blockIdx.x; int l = threadIdx.x;
    int row = b*N_ + l;
    float xd0=0.f,xd1=0.f,xd2=0.f,nm=0.f;
    if (l < N_) {
        nm = nmask[row];
        xd0 = (x[(size_t)row*3+0]-x_in[(size_t)row*3+0])*nm;
        xd1 = (x[(size_t)row*3+1]-x_in[(size_t)row*3+1])*nm;
        xd2 = (x[(size_t)row*3+2]-x_in[(size_t)row*3+2])*nm;
    }
    float s0=xd0,s1=xd1,s2=xd2,sn=nm;
    #pragma unroll
    for (int off=32; off; off>>=1) {
        s0+=__shfl_xor(s0,off,64); s1+=__shfl_xor(s1,off,64);
        s2+=__shfl_xor(s2,off,64); sn+=__shfl_xor(sn,off,64);
    }
    float m0=s0/sn, m1=s1/sn, m2=s2/sn;
    if (l < N_) {
        out[(size_t)row*8+0]=(xd0-m0)*nm;
        out[(size_t)row*8+1]=(xd1-m1)*nm;
        out[(size_t)row*8+2]=(xd2-m2)*nm;
    }
}

__global__ void k_out_h(const float* __restrict__ h, const float* __restrict__ wout_w, const float* __restrict__ wout_b,
                        const float* __restrict__ nmask, float* __restrict__ out)
{
    int row = blockIdx.x; int lane = threadIdx.x;
    int c4 = lane<<2;
    float4 hv = *(const float4*)(h + (size_t)row*H_ + c4);
    float p0=0,p1=0,p2=0,p3=0,p4=0;
    float hvv[4] = {hv.x,hv.y,hv.z,hv.w};
    #pragma unroll
    for (int j=0;j<4;j++) {
        int k = c4+j;
        float hval = hvv[j];
        p0 += hval * wout_w[k*6+0];
        p1 += hval * wout_w[k*6+1];
        p2 += hval * wout_w[k*6+2];
        p3 += hval * wout_w[k*6+3];
        p4 += hval * wout_w[k*6+4];
    }
    #pragma unroll
    for (int off=32; off; off>>=1) {
        p0+=__shfl_xor(p0,off,64); p1+=__shfl_xor(p1,off,64); p2+=__shfl_xor(p2,off,64);
        p3+=__shfl_xor(p3,off,64); p4+=__shfl_xor(p4,off,64);
    }
    if (lane==0) {
        float nm = nmask[row];
        out[(size_t)row*8+3] = (p0+wout_b[0])*nm;
        out[(size_t)row*8+4] = (p1+wout_b[1])*nm;
        out[(size_t)row*8+5] = (p2+wout_b[2])*nm;
        out[(size_t)row*8+6] = (p3+wout_b[3])*nm;
        out[(size_t)row*8+7] = (p4+wout_b[4])*nm;
    }
}

extern "C" void kernel_launch(void* const* d_in, const int* in_sizes, int n_in,
                              void* d_out, int out_size, void* d_ws, size_t ws_size,
                              hipStream_t stream)
{
    const float* x_in  = (const float*)d_in[0];
    const float* h_in  = (const float*)d_in[1];
    const float* t     = (const float*)d_in[2];
    const float* nmask = (const float*)d_in[3];
    const float* emask = (const float*)d_in[4];
    const int*   eidx  = (const int*)d_in[5];
    const float* win_w = (const float*)d_in[6];
    const float* win_b = (const float*)d_in[7];
    const float* wout_w= (const float*)d_in[8];
    const float* wout_b= (const float*)d_in[9];
    const float* e_w1  = (const float*)d_in[10];
    const float* e_b1  = (const float*)d_in[11];
    const float* e_w2  = (const float*)d_in[12];
    const float* e_b2  = (const float*)d_in[13];
    const float* att_w = (const float*)d_in[14];
    const float* att_b = (const float*)d_in[15];
    const float* h_w1  = (const float*)d_in[16];
    const float* h_b1  = (const float*)d_in[17];
    const float* h_w2  = (const float*)d_in[18];
    const float* h_b2  = (const float*)d_in[19];
    const float* x_w1  = (const float*)d_in[20];
    const float* x_b1  = (const float*)d_in[21];
    const float* x_w2  = (const float*)d_in[22];
    const float* x_b2  = (const float*)d_in[23];
    const float* x_w3  = (const float*)d_in[24];
    float* out = (float*)d_out;

    char* ws = (char*)d_ws;
    size_t off = 0;
    auto alloc = [&](size_t bytes)->float* {
        float* p = (float*)(ws + off);
        off = (off + bytes + 255) & ~(size_t)255;
        return p;
    };
    float* h    = alloc((size_t)BN_*H_*4);
    float* xA   = alloc((size_t)BN_*3*4);
    float* xB   = alloc((size_t)BN_*3*4);
    float* a    = alloc((size_t)BE_*4);
    float* pdU  = alloc((size_t)4*BE_*4);
    float* pdM  = alloc((size_t)4*BE_*4);
    float* NB5  = alloc((size_t)5*BN_*H_*4);
    float* agg  = alloc((size_t)BN_*H_*4);
    float* hm1  = alloc((size_t)BN_*H_*4);
    // fragmentized W (bf16 hi/lo), all layers, both passes: L * 131072 ushorts each
    ushort* WfU = (ushort*)alloc((size_t)L_*131072*sizeof(ushort));
    ushort* WfM = (ushort*)alloc((size_t)L_*131072*sizeof(ushort));

    // chunk the big edge activation buffers (u1,m1 bf16 hi/lo fragment planes; M2 fp32) to fit ws_size
    size_t avail = (ws_size > off + (2<<20)) ? (ws_size - off - (2<<20)) : 0;
    long ce_cap = (long)(avail / ((size_t)3*H_*4));
    long gcap = ce_cap / DEG_;
    if (gcap < 1) gcap = 1;
    if (gcap > BN_) gcap = BN_;
    int nc  = (int)((BN_ + gcap - 1)/gcap);
    int gpc = (BN_ + nc - 1)/nc;
    int cecap = gpc*DEG_;
    int nrbcap = (cecap+63)/64;
    size_t planeElems = (size_t)nrbcap*16384;    // ushorts per plane
    ushort* u1h = (ushort*)alloc(planeElems*2*sizeof(ushort));  // hi + lo
    ushort* u1l = u1h + planeElems;
    ushort* m1h = (ushort*)alloc(planeElems*2*sizeof(ushort));
    ushort* m1l = m1h + planeElems;
    float*  M2  = alloc((size_t)cecap*H_*4);

    k_init_h<<<BN_, H_, 0, stream>>>(h_in, t, win_w, win_b, h);
    k_init_xa<<<(BE_+255)/256, 256, 0, stream>>>(x_in, eidx, emask, xA, a);
    k_wprep<<<(L_*2*8192+255)/256, 256, 0, stream>>>(x_w2, e_w2, WfU, WfM);

    float* x_cur = xA;
    float* x_new = xB;

    for (int l=0; l<L_; l++) {
        const float* xw1l = x_w1 + (size_t)l*514*H_;
        const float* ew1l = e_w1 + (size_t)l*514*H_;
        const float* hw1l = h_w1 + (size_t)l*512*H_;

        // 5 node-side GEMMs sharing A=h: XHi, XHj, EHi, EHj, Htop
        GArgs na = {};
        const float* Bz[5] = { xw1l, xw1l+(size_t)256*H_, ew1l, ew1l+(size_t)256*H_, hw1l };
        for (int z=0;z<5;z++){
            na.g[z].A=h; na.g[z].Bw=Bz[z]; na.g[z].bias=nullptr; na.g[z].add=nullptr;
            na.g[z].rmask=nullptr; na.g[z].C=NB5 + (size_t)z*BN_*H_;
        }
        k_gemm64<0><<<dim3(BN_/64, H_/64, 5),256,0,stream>>>(na, BN_, H_);

        float* XHi=NB5;
        float* XHj=NB5+(size_t)BN_*H_;
        float* EHi=NB5+(size_t)2*BN_*H_;
        float* EHj=NB5+(size_t)3*BN_*H_;
        float* Htop=NB5+(size_t)4*BN_*H_;

        for (int c=0;c<nc;c++) {
            int g0 = c*gpc;
            int g1 = (g0+gpc < BN_) ? (g0+gpc) : BN_;
            int ng = g1-g0;
            if (ng <= 0) break;
            int e0 = g0*DEG_; int ce = ng*DEG_;
            int nrb = (ce+63)/64;

            k_edge_mlp1<<<nrb*8,256,0,stream>>>(XHi,XHj,EHi,EHj, x_cur, a, eidx, emask,
                xw1l+(size_t)512*H_, xw1l+(size_t)513*H_, x_b1+(size_t)l*H_,
                ew1l+(size_t)512*H_, ew1l+(size_t)513*H_, e_b1+(size_t)l*H_,
                u1h, u1l, m1h, m1l, e0, ce, nrb);

            EArgs2 ea = {};
            ea.g[0] = { u1h, u1l, WfU + (size_t)l*131072, x_b2+(size_t)l*H_, x_w3+(size_t)l*H_,  nullptr, pdU };
            ea.g[1] = { m1h, m1l, WfM + (size_t)l*131072, e_b2+(size_t)l*H_, att_w+(size_t)l*H_, M2,      pdM };
            k_edge_gemm_mfma<<<dim3(nrb, 1, 2),256,0,stream>>>(ea, e0, ce);

            k_scatter2<<<ng,256,0,stream>>>(M2, pdU, pdM, att_b+l, x_cur, x_new,
                                            eidx, emask, nmask, agg, g0, e0);
        }

        GArgs ha = {};
        ha.g[0] = { agg, hw1l+(size_t)256*H_, h_b1+(size_t)l*H_, Htop, nullptr, hm1 };
        k_gemm64<1><<<dim3(BN_/64,H_/64,1),256,0,stream>>>(ha, BN_, H_);

        GArgs h2 = {};
        h2.g[0] = { hm1, h_w2+(size_t)l*H_*H_, h_b2+(size_t)l*H_, h, nmask, h };
        k_gemm64<0><<<dim3(BN_/64,H_/64,1),256,0,stream>>>(h2, BN_, H_);

        float* tmp = x_cur; x_cur = x_new; x_new = tmp;
    }

    k_out_x<<<B_,64,0,stream>>>(x_cur, x_in, nmask, out);
    k_out_h<<<BN_,64,0,stream>>>(h, wout_w, wout_b, nmask, out);
}